// Round 1
// baseline (1998.044 us; speedup 1.0000x reference)
//
#include <hip/hip_runtime.h>
#include <hip/hip_bf16.h>

typedef __bf16 bf16_t;
typedef __attribute__((ext_vector_type(8))) __bf16 bf16x8;
typedef __attribute__((ext_vector_type(4))) __bf16 bf16x4;
typedef __attribute__((ext_vector_type(4))) float f32x4;

#define NROWS 32768
#define FEAT  4096
#define INDIM 4097
#define HID   2048
#define PROJ  512
#define NPAD  33024   /* 258 tiles * 128 */
#define MTILES 258
#define SENT  0xFFFFFFFFu

// ---------------------------------------------------------------- utilities
__device__ __forceinline__ void load_lds16(const bf16_t* g, char* s) {
  // async global->LDS, 16B/lane. LDS dest is wave-uniform base + lane*16.
  __builtin_amdgcn_global_load_lds(
      (__attribute__((address_space(1))) void*)(void*)g,
      (__attribute__((address_space(3))) void*)s, 16, 0, 0);
}

// ---------------------------------------------------------------- prep
__global__ __launch_bounds__(256) void init_kernel(unsigned* __restrict__ perm,
                                                   int* __restrict__ cnt) {
  int i = blockIdx.x * 256 + threadIdx.x;
  if (i < NPAD) perm[i] = SENT;
  if (i < 4) cnt[i] = 0;
}

__global__ __launch_bounds__(256) void count_kernel(const float* __restrict__ x,
                                                    int* __restrict__ cnt) {
  int i = blockIdx.x * 256 + threadIdx.x;
  if (i >= NROWS) return;
  float f = x[(long)i * INDIM + FEAT];
  if (f > 0.5f) atomicAdd(&cnt[0], 1);
}

__global__ __launch_bounds__(256) void scatter_kernel(const float* __restrict__ x,
                                                      unsigned* __restrict__ perm,
                                                      int* __restrict__ cnt) {
  int i = blockIdx.x * 256 + threadIdx.x;
  if (i >= NROWS) return;
  float f = x[(long)i * INDIM + FEAT];
  int g = (f > 0.5f) ? 0 : 1;                 // 0 = nat, 1 = oth
  int pos = atomicAdd(&cnt[1 + g], 1);
  int off_oth = ((cnt[0] + 127) >> 7) << 7;   // cnt[0] final (prev kernel)
  int q = (g == 0) ? pos : off_oth + pos;
  perm[q] = (unsigned)i;
}

// x (fp32, pitch 4097, drop flag col) -> xbf (bf16, pitch 4096)
// one wave handles 512 consecutive elements (fits inside one row: 512 | 4096)
__global__ __launch_bounds__(256) void convert_x_kernel(const float* __restrict__ x,
                                                        bf16_t* __restrict__ xbf) {
  const int lane = threadIdx.x & 63;
  const long wid = ((long)blockIdx.x * 256 + threadIdx.x) >> 6;
  const long chunk = wid * 512;
  const long row = chunk >> 12;          // /4096
  const long col = chunk & 4095;
  const float* src = x + row * INDIM + col + lane;
  bf16_t* dst = xbf + chunk + lane;
#pragma unroll
  for (int j = 0; j < 8; ++j)
    dst[j * 64] = (bf16_t)src[j * 64];
}

// W[K][N] fp32 -> Wt[N][K] bf16, 32x32 LDS tiles
__global__ __launch_bounds__(256) void transpose_convert_kernel(
    const float* __restrict__ W, bf16_t* __restrict__ Wt, int K, int N) {
  __shared__ float tile[32][33];
  const int n0 = blockIdx.x << 5;
  const int k0 = blockIdx.y << 5;
  const int t = threadIdx.x;
  const int r = t >> 3;
  const int c4 = (t & 7) << 2;
  f32x4 v = *(const f32x4*)(W + (long)(k0 + r) * N + n0 + c4);
#pragma unroll
  for (int i = 0; i < 4; ++i) tile[r][c4 + i] = v[i];
  __syncthreads();
  bf16x4 o;
#pragma unroll
  for (int i = 0; i < 4; ++i) o[i] = (bf16_t)tile[c4 + i][r];
  *(bf16x4*)(Wt + (long)(n0 + r) * K + k0 + c4) = o;
}

// ---------------------------------------------------------------- GEMM
// C[M][N] = A[M][K] @ B[K][N] (+bias), B supplied transposed: Bt[N][K].
// 128x128 tile, BK=32, 256 thr = 4 waves (2x2 of 64x64), 16x16x32 bf16 MFMA.
// A rows gathered via perm (GATHER) or direct padded index.
template <bool GATHER, bool RELU_BF16>
__global__ __launch_bounds__(256) void gemm_kernel(
    const bf16_t* __restrict__ A,
    const bf16_t* __restrict__ BtNat, const bf16_t* __restrict__ BtOth,
    const float* __restrict__ biasNat, const float* __restrict__ biasOth,
    void* __restrict__ Cout,
    const unsigned* __restrict__ perm, const int* __restrict__ cnt,
    const int K, const int N) {
  __shared__ char smem[16384];          // A tile 8KB | B tile 8KB
  const int tid = threadIdx.x;
  const int tile_m = blockIdx.y;
  const int qbase = tile_m << 7;
  if (perm[qbase] == SENT) return;      // inactive tile (uniform per block)
  const int n0 = blockIdx.x << 7;
  const int n_nat = cnt[0];
  const int m_tiles_nat = (n_nat + 127) >> 7;
  const bool nat = (tile_m < m_tiles_nat);
  const bf16_t* __restrict__ Bt = nat ? BtNat : BtOth;
  const float* __restrict__ bias = nat ? biasNat : biasOth;

  // staging: 512 16B-chunks per 8KB tile; chunk c -> row c>>2, 16B piece c&3
  const int r0 = tid >> 2;
  const int kc = tid & 3;
  long arow0, arow1;
  if (GATHER) {
    unsigned p0 = perm[qbase + r0];
    unsigned p1 = perm[qbase + r0 + 64];
    arow0 = (p0 == SENT) ? 0 : (long)p0;  // pad rows read row 0 (harmless)
    arow1 = (p1 == SENT) ? 0 : (long)p1;
  } else {
    arow0 = qbase + r0;
    arow1 = qbase + r0 + 64;
  }
  const bf16_t* srcA0 = A + arow0 * K + (kc << 3);
  const bf16_t* srcA1 = A + arow1 * K + (kc << 3);
  const bf16_t* srcB0 = Bt + (long)(n0 + r0) * K + (kc << 3);
  const bf16_t* srcB1 = Bt + (long)(n0 + r0 + 64) * K + (kc << 3);

  const int wave = tid >> 6;
  const int lane = tid & 63;
  const int quad = lane >> 4;
  const int l16 = lane & 15;
  const int wm = (wave >> 1) << 6;
  const int wn = (wave & 1) << 6;

  char* const Alds = smem;
  char* const Blds = smem + 8192;
  char* const dstA0 = Alds + (wave << 10);
  char* const dstA1 = Alds + 4096 + (wave << 10);
  char* const dstB0 = Blds + (wave << 10);
  char* const dstB1 = Blds + 4096 + (wave << 10);

  f32x4 acc[4][4] = {};

  const int kiters = K >> 5;
  for (int kt = 0; kt < kiters; ++kt) {
    __syncthreads();                     // prev iter's ds_reads drained
    load_lds16(srcA0, dstA0);
    load_lds16(srcA1, dstA1);
    load_lds16(srcB0, dstB0);
    load_lds16(srcB1, dstB1);
    srcA0 += 32; srcA1 += 32; srcB0 += 32; srcB1 += 32;
    __syncthreads();                     // vmcnt(0) drain -> LDS filled
    bf16x8 af[4], bfr[4];
#pragma unroll
    for (int i = 0; i < 4; ++i)
      af[i] = *(const bf16x8*)(Alds + (((wm + (i << 4) + l16) << 5) + (quad << 3)) * 2);
#pragma unroll
    for (int i = 0; i < 4; ++i)
      bfr[i] = *(const bf16x8*)(Blds + (((wn + (i << 4) + l16) << 5) + (quad << 3)) * 2);
#pragma unroll
    for (int mi = 0; mi < 4; ++mi)
#pragma unroll
      for (int ni = 0; ni < 4; ++ni)
        acc[mi][ni] = __builtin_amdgcn_mfma_f32_16x16x32_bf16(af[mi], bfr[ni], acc[mi][ni], 0, 0, 0);
  }

  float bv[4];
#pragma unroll
  for (int ni = 0; ni < 4; ++ni) bv[ni] = bias[n0 + wn + (ni << 4) + l16];

  // C/D layout: col = lane&15, row = quad*4 + reg  (m89-verified)
#pragma unroll
  for (int mi = 0; mi < 4; ++mi) {
#pragma unroll
    for (int ni = 0; ni < 4; ++ni) {
#pragma unroll
      for (int r = 0; r < 4; ++r) {
        const int m = wm + (mi << 4) + (quad << 2) + r;
        const int col = n0 + wn + (ni << 4) + l16;
        float v = acc[mi][ni][r] + bv[ni];
        if (RELU_BF16) {
          v = fmaxf(v, 0.0f);
          ((bf16_t*)Cout)[(long)(qbase + m) * N + col] = (bf16_t)v;
        } else {
          ((float*)Cout)[(long)(qbase + m) * N + col] = v;
        }
      }
    }
  }
}

// ---------------------------------------------------------------- epilogue
// per padded row q: norm(z), z/max(norm,eps) scatter; logits = relu(z)@Wc+bc
__global__ __launch_bounds__(256) void epilogue_kernel(
    const float* __restrict__ z,                       // [NPAD][512]
    const float* __restrict__ Wc0, const float* __restrict__ bc0,
    const float* __restrict__ Wc1, const float* __restrict__ bc1,
    const unsigned* __restrict__ perm, const int* __restrict__ cnt,
    float* __restrict__ out_z, float* __restrict__ out_logits) {
  __shared__ float WcL[2][PROJ * 3];
  for (int i = threadIdx.x; i < PROJ * 3; i += 256) {
    WcL[0][i] = Wc0[i];
    WcL[1][i] = Wc1[i];
  }
  __syncthreads();
  const int wave = threadIdx.x >> 6;
  const int lane = threadIdx.x & 63;
  const int q = blockIdx.x * 4 + wave;
  const unsigned orig = perm[q];
  if (orig == SENT) return;             // pad row
  const int n_nat = cnt[0];
  const int off_oth = ((n_nat + 127) >> 7) << 7;
  const int g = (q < off_oth) ? 0 : 1;

  float zv[8];
  float ss = 0.f, l0 = 0.f, l1 = 0.f, l2 = 0.f;
#pragma unroll
  for (int i = 0; i < 8; ++i) {
    const int k = i * 64 + lane;        // lane-stride 1 -> Wc LDS 2-way (free)
    float v = z[(long)q * PROJ + k];
    zv[i] = v;
    ss += v * v;
    float r = fmaxf(v, 0.f);
    const float* w = &WcL[g][k * 3];
    l0 += r * w[0];
    l1 += r * w[1];
    l2 += r * w[2];
  }
#pragma unroll
  for (int off = 32; off > 0; off >>= 1) {
    ss += __shfl_xor(ss, off);
    l0 += __shfl_xor(l0, off);
    l1 += __shfl_xor(l1, off);
    l2 += __shfl_xor(l2, off);
  }
  const float inv = 1.f / fmaxf(sqrtf(ss), 1e-12f);
#pragma unroll
  for (int i = 0; i < 8; ++i)
    out_z[(long)orig * PROJ + i * 64 + lane] = zv[i] * inv;
  if (lane == 0) {
    const float* bc = g ? bc1 : bc0;
    out_logits[(long)orig * 3 + 0] = l0 + bc[0];
    out_logits[(long)orig * 3 + 1] = l1 + bc[1];
    out_logits[(long)orig * 3 + 2] = l2 + bc[2];
  }
}

// ---------------------------------------------------------------- launch
extern "C" void kernel_launch(void* const* d_in, const int* in_sizes, int n_in,
                              void* d_out, int out_size, void* d_ws, size_t ws_size,
                              hipStream_t stream) {
  const float* x   = (const float*)d_in[0];
  const float* W1n = (const float*)d_in[1];
  const float* b1n = (const float*)d_in[2];
  const float* W2n = (const float*)d_in[3];
  const float* b2n = (const float*)d_in[4];
  const float* Wcn = (const float*)d_in[5];
  const float* bcn = (const float*)d_in[6];
  const float* W1o = (const float*)d_in[7];
  const float* b1o = (const float*)d_in[8];
  const float* W2o = (const float*)d_in[9];
  const float* b2o = (const float*)d_in[10];
  const float* Wco = (const float*)d_in[11];
  const float* bco = (const float*)d_in[12];

  char* ws = (char*)d_ws;
  // ws layout (total ~441.6 MB); z_ws aliases xbf (xbf dead after GEMM1)
  bf16_t* xbf  = (bf16_t*)ws;                                   // 268,435,456
  float*  z_ws = (float*)ws;                                    // 67,633,152 (alias)
  size_t off = 268435456;
  bf16_t* W1tn = (bf16_t*)(ws + off); off += (size_t)FEAT * HID * 2;   // 16 MB
  bf16_t* W1to = (bf16_t*)(ws + off); off += (size_t)FEAT * HID * 2;
  bf16_t* W2tn = (bf16_t*)(ws + off); off += (size_t)HID * PROJ * 2;   // 2 MB
  bf16_t* W2to = (bf16_t*)(ws + off); off += (size_t)HID * PROJ * 2;
  bf16_t* h_ws = (bf16_t*)(ws + off); off += (size_t)NPAD * HID * 2;   // 135 MB
  unsigned* perm = (unsigned*)(ws + off); off += (size_t)NPAD * 4;
  int* cnt = (int*)(ws + off);

  float* out_z = (float*)d_out;
  float* out_logits = out_z + (size_t)NROWS * PROJ;

  // 1) partition rows by flag (padded, sentinel-filled perm)
  init_kernel<<<(NPAD + 255) / 256, 256, 0, stream>>>(perm, cnt);
  count_kernel<<<NROWS / 256, 256, 0, stream>>>(x, cnt);
  scatter_kernel<<<NROWS / 256, 256, 0, stream>>>(x, perm, cnt);

  // 2) dtype conversions
  convert_x_kernel<<<(int)(((long)NROWS * FEAT / 512) / 4), 256, 0, stream>>>(x, xbf);
  transpose_convert_kernel<<<dim3(HID / 32, FEAT / 32), 256, 0, stream>>>(W1n, W1tn, FEAT, HID);
  transpose_convert_kernel<<<dim3(HID / 32, FEAT / 32), 256, 0, stream>>>(W1o, W1to, FEAT, HID);
  transpose_convert_kernel<<<dim3(PROJ / 32, HID / 32), 256, 0, stream>>>(W2n, W2tn, HID, PROJ);
  transpose_convert_kernel<<<dim3(PROJ / 32, HID / 32), 256, 0, stream>>>(W2o, W2to, HID, PROJ);

  // 3) h = relu(feat @ W1 + b1)  (gathered A rows, bf16 out)
  gemm_kernel<true, true><<<dim3(HID / 128, MTILES), 256, 0, stream>>>(
      xbf, W1tn, W1to, b1n, b1o, (void*)h_ws, perm, cnt, FEAT, HID);

  // 4) z = h @ W2 + b2  (fp32 out, overwrites dead xbf region)
  gemm_kernel<false, false><<<dim3(PROJ / 128, MTILES), 256, 0, stream>>>(
      h_ws, W2tn, W2to, b2n, b2o, (void*)z_ws, perm, cnt, HID, PROJ);

  // 5) normalize + classifier, scatter to original row order
  epilogue_kernel<<<NPAD / 4, 256, 0, stream>>>(
      z_ws, Wcn, bcn, Wco, bco, perm, cnt, out_z, out_logits);
}